// Round 10
// baseline (513.227 us; speedup 1.0000x reference)
//
#include <hip/hip_runtime.h>
#include <math.h>

#define N_EDGES 4096
#define NN1 256
#define NN2 128

// ---------------- reduction helpers ----------------
template<int NT>
__device__ inline float block_sum(float v, float* red, int t){
  red[t] = v; __syncthreads();
  #pragma unroll
  for (int st = NT/2; st > 0; st >>= 1){
    if (t < st) red[t] += red[t+st];
    __syncthreads();
  }
  float r = red[0]; __syncthreads();
  return r;
}
template<int NT>
__device__ inline float block_max(float v, float* red, int t){
  red[t] = v; __syncthreads();
  #pragma unroll
  for (int st = NT/2; st > 0; st >>= 1){
    if (t < st) red[t] = fmaxf(red[t], red[t+st]);
    __syncthreads();
  }
  float r = red[0]; __syncthreads();
  return r;
}
template<int NT>
__device__ inline int block_min_int(int v, int* red, int t){
  red[t] = v; __syncthreads();
  #pragma unroll
  for (int st = NT/2; st > 0; st >>= 1){
    if (t < st) red[t] = min(red[t], red[t+st]);
    __syncthreads();
  }
  int r = red[0]; __syncthreads();
  return r;
}

// ---------------- conv3x3(SAME): 16x16 tile, 2x2 pts/thread, CPT=4, broadcast weights ----
// Block 256 thr = 4 waves. Tile = 16x16 conv points (8x8 pooled). Thread (qx,qy):
// conv pts (2qx+dx, 2qy+dy) for 4 couts (wave wv owns couts cg*16+wv*4+0..3).
// Patch 4x4 -> 8 ds_read_b64 (TROW=20: 2-way-max bank aliasing, free).
// Weights packed [c][k][co16] -> 9 broadcast b128 per channel. 144 FMA / 17 LDS instr.
// Input pre-padded [CIN][H+2][in_row], zero border. Register-prefetch dbuf pipeline,
// hoisted descriptors, single barrier per chunk.
// SPLITK==1: fused bias+relu+pool2x2 -> pitched (padded-interior or raw) out.
// SPLITK>1 : raw conv partials [split][COUT][H][W].
template<int CIN, int COUT, int CHUNK, int SPLITK>
__global__ __launch_bounds__(256) void conv10(
    const float* __restrict__ in, const float* __restrict__ w,
    const float* __restrict__ bias, float* __restrict__ out,
    int H, int W, int in_row, int in_ch, int out_row, int out_ch)
{
  constexpr int CPB  = CIN / SPLITK;
  constexpr int NCH  = CPB / CHUNK;
  constexpr int CGRPS = COUT / 16;
  constexpr int TROW = 20;                 // 18 cols staged as 5 float4
  constexpr int TSZ  = CHUNK * 18 * TROW;
  constexpr int WSZ  = CHUNK * 9 * 16;
  constexpr int TJ   = CHUNK * 18 * 5;     // float4 tile jobs
  constexpr int WN   = CHUNK * 9 * 16;     // weight scalar jobs
  constexpr int NST  = (TJ + 255) / 256;
  constexpr int NSW  = (WN + 255) / 256;
  __shared__ float tile[2][TSZ];
  __shared__ float wlds[2][WSZ];

  const int cg = blockIdx.x % CGRPS;       // fastest-varying: tile re-reads are cache-hot
  const int bx = blockIdx.x / CGRPS;
  const int by = blockIdx.y;
  const int split = blockIdx.z;
  const int tid = threadIdx.x;
  const int lane = tid & 63;
  const int wv = tid >> 6;
  const int qx = lane & 7, qy = lane >> 3;
  const int c_base = split * CPB;

  // hoisted staging descriptors (chunk-invariant); -1 = inactive slot
  int tsrc[NST], tlds[NST];
  #pragma unroll
  for (int s2 = 0; s2 < NST; ++s2){
    int j = tid + s2*256;
    if (j < TJ){
      int row = j / 5, part = j - row*5;
      int c = row / 18, rr = row - c*18;
      tsrc[s2] = (c_base + c)*in_ch + (16*by + rr)*in_row + 16*bx + 4*part;
      tlds[s2] = (c*18 + rr)*TROW + 4*part;
    } else { tsrc[s2] = -1; tlds[s2] = 0; }
  }
  int wsrc[NSW], wldo[NSW];
  #pragma unroll
  for (int s2 = 0; s2 < NSW; ++s2){
    int e = tid + s2*256;
    if (e < WN){
      int co = e / (CHUNK*9);
      int rem = e - co*(CHUNK*9);
      int c = rem / 9, k = rem - c*9;
      wsrc[s2] = ((cg*16 + co)*CIN + c_base + c)*9 + k;
      wldo[s2] = (c*9 + k)*16 + co;        // [c][k][co16]
    } else { wsrc[s2] = -1; wldo[s2] = 0; }
  }

  float acc[4][4];
  #pragma unroll
  for (int co = 0; co < 4; ++co){
    acc[co][0]=0.f; acc[co][1]=0.f; acc[co][2]=0.f; acc[co][3]=0.f;
  }

  float4 rt[NST];
  float  rw[NSW];

  auto LD = [&](int c0){
    #pragma unroll
    for (int s2 = 0; s2 < NST; ++s2)
      if (tsrc[s2] >= 0) rt[s2] = *(const float4*)&in[tsrc[s2] + c0*in_ch];
    #pragma unroll
    for (int s2 = 0; s2 < NSW; ++s2)
      if (wsrc[s2] >= 0) rw[s2] = w[wsrc[s2] + c0*9];
  };
  auto ST = [&](int b){
    #pragma unroll
    for (int s2 = 0; s2 < NST; ++s2)
      if (tsrc[s2] >= 0) *(float4*)&tile[b][tlds[s2]] = rt[s2];
    #pragma unroll
    for (int s2 = 0; s2 < NSW; ++s2)
      if (wsrc[s2] >= 0) wlds[b][wldo[s2]] = rw[s2];
  };
  auto COMPUTE = [&](int b){
    #pragma unroll
    for (int c = 0; c < CHUNK; ++c){
      float p[4][4];
      const int tb = (c*18 + 2*qy)*TROW + 2*qx;
      #pragma unroll
      for (int i = 0; i < 4; ++i){
        float2 lo = *(const float2*)&tile[b][tb + i*TROW];
        float2 hi = *(const float2*)&tile[b][tb + i*TROW + 2];
        p[i][0]=lo.x; p[i][1]=lo.y; p[i][2]=hi.x; p[i][3]=hi.y;
      }
      #pragma unroll
      for (int k = 0; k < 9; ++k){
        const int ky = k / 3, kx = k - ky*3;
        float4 wk = *(const float4*)&wlds[b][(c*9 + k)*16 + wv*4];  // broadcast
        float wa[4] = {wk.x, wk.y, wk.z, wk.w};
        #pragma unroll
        for (int co = 0; co < 4; ++co)
          #pragma unroll
          for (int dy = 0; dy < 2; ++dy)
            #pragma unroll
            for (int dx = 0; dx < 2; ++dx)
              acc[co][dy*2+dx] += wa[co] * p[dy+ky][dx+kx];
      }
    }
  };

  LD(0); ST(0); __syncthreads();
  for (int ch = 0; ch < NCH; ++ch){
    if (ch + 1 < NCH) LD((ch+1)*CHUNK);   // next-chunk loads in flight
    COMPUTE(ch & 1);
    if (ch + 1 < NCH){
      ST((ch+1) & 1);                     // other buffer: safe before barrier
      __syncthreads();
    }
  }

  if (SPLITK == 1){
    #pragma unroll
    for (int co = 0; co < 4; ++co){
      int cout = cg*16 + wv*4 + co;
      float m = fmaxf(fmaxf(acc[co][0],acc[co][1]), fmaxf(acc[co][2],acc[co][3])) + bias[cout];
      int oy = 8*by + qy, ox = 8*bx + qx;
      out[cout*out_ch + oy*out_row + ox] = fmaxf(m, 0.f);
    }
  } else {
    #pragma unroll
    for (int co = 0; co < 4; ++co){
      int cout = cg*16 + wv*4 + co;
      float* pb = out + (split*COUT + cout)*H*W;
      #pragma unroll
      for (int dy = 0; dy < 2; ++dy){
        int y = 16*by + 2*qy + dy, x0 = 16*bx + 2*qx;
        *(float2*)&pb[y*W + x0] = make_float2(acc[co][dy*2], acc[co][dy*2+1]);
      }
    }
  }
}

// sum fp32 partials over splits, then bias + relu + maxpool2x2 -> pitched out
template<int SPLITK>
__global__ __launch_bounds__(256) void reduce_pool(
    const float* __restrict__ pbuf, const float* __restrict__ bias,
    float* __restrict__ out, int COUT, int H, int W, int out_row, int out_ch)
{
  int idx = blockIdx.x*256 + threadIdx.x;
  const int OW = W >> 1, OH = H >> 1;
  if (idx >= COUT*OH*OW) return;
  int px = idx % OW; int t = idx / OW; int py = t % OH; int cout = t / OH;
  unsigned base = (unsigned)cout*H*W + (unsigned)(2*py)*W + 2*px;
  unsigned sstr = (unsigned)COUT*H*W;
  float s00=0.f, s01=0.f, s10=0.f, s11=0.f;
  #pragma unroll
  for (int s=0;s<SPLITK;s++){
    const float* pb = pbuf + s*sstr + base;
    s00 += pb[0]; s01 += pb[1]; s10 += pb[W]; s11 += pb[W+1];
  }
  float m = fmaxf(fmaxf(s00,s01),fmaxf(s10,s11)) + bias[cout];
  out[cout*out_ch + py*out_row + px] = fmaxf(m, 0.f);
}

// ---------------- prep: pad input + transpose 4 sage weight matrices ----------------
__global__ __launch_bounds__(256) void prep_kernel(const float* __restrict__ src,
    float* __restrict__ dst,
    const float* __restrict__ a, const float* __restrict__ b2,
    const float* __restrict__ c2, const float* __restrict__ d2,
    float* __restrict__ o)
{
  int b = blockIdx.x, tid = threadIdx.x;
  if (b < 1280){
    int idx = b*256 + tid;               // 5*512*128 float4 jobs
    int c = idx >> 16;
    int rem = idx & 65535;
    int y = rem >> 7, xq = rem & 127;
    float4 v = *(const float4*)&src[c*262144 + y*512 + 4*xq];
    float* d = &dst[c*(514*516) + (y+1)*516 + 1 + 4*xq];
    d[0]=v.x; d[1]=v.y; d[2]=v.z; d[3]=v.w;
  } else {
    int idx = (b - 1280)*256 + tid;      // 4*128*256 = 131072 jobs
    int m = idx >> 15;
    int rem = idx & 32767;
    int k = rem >> 7, cc = rem & 127;
    const float* sp = (m==0)?a:(m==1)?b2:(m==2)?c2:d2;
    o[m*32768 + k*128 + cc] = sp[cc*256 + k];
  }
}

// ---------------- graph kernels ----------------
__global__ void build_adj_kernel(const int* __restrict__ ei, float* adj, float* cnt){
  int e = blockIdx.x*256 + threadIdx.x;
  if (e < N_EDGES){
    int s = ei[e], d = ei[N_EDGES + e];
    atomicAdd(&adj[s*NN1 + d], 1.0f);   // integer-valued -> order independent
    atomicAdd(&cnt[d], 1.0f);
  }
}

__global__ __launch_bounds__(256) void agg_kernel(const float* __restrict__ adj,
    const float* __restrict__ cnt, const float* __restrict__ org, float* __restrict__ aggn){
  int d = blockIdx.x, j = threadIdx.x;
  float acc = 0.f;
  for (int s = 0; s < NN1; ++s){
    float a = adj[s*NN1 + d];
    if (a != 0.f) acc += a * org[s*NN1 + j];
  }
  aggn[d*NN1 + j] = acc / fmaxf(cnt[d], 1.0f);
}

// transposed-weight sage12: coalesced weight reads; also writes s^T
__global__ __launch_bounds__(128) void sage12_kernel(
    const float* __restrict__ aggn, const float* __restrict__ org,
    const float* __restrict__ wl1t, const float* __restrict__ bl1, const float* __restrict__ wr1t,
    const float* __restrict__ wl2t, const float* __restrict__ bl2, const float* __restrict__ wr2t,
    float* __restrict__ x1, float* __restrict__ s_out, float* __restrict__ st,
    float* __restrict__ entpart)
{
  __shared__ float sa[NN1], so[NN1], red[128];
  int n = blockIdx.x, c = threadIdx.x;
  for (int k = c; k < NN1; k += 128){ sa[k] = aggn[n*NN1+k]; so[k] = org[n*NN1+k]; }
  __syncthreads();
  float p1 = bl1[c], p2 = bl2[c];
  for (int k = 0; k < NN1; ++k){
    float av = sa[k], ov = so[k];
    p1 += av*wl1t[k*128+c] + ov*wr1t[k*128+c];
    p2 += av*wl2t[k*128+c] + ov*wr2t[k*128+c];
  }
  float n1s = block_sum<128>(p1*p1, red, c);
  x1[n*128 + c] = p1 / fmaxf(sqrtf(n1s), 1e-12f);
  float n2s = block_sum<128>(p2*p2, red, c);
  float p2n = p2 / fmaxf(sqrtf(n2s), 1e-12f);
  float mx = block_max<128>(p2n, red, c);
  float ev = expf(p2n - mx);
  float ssum = block_sum<128>(ev, red, c);
  float sv = ev / ssum;
  s_out[n*128 + c] = sv;
  st[c*NN1 + n] = sv;
  float esum = block_sum<128>(-sv * logf(sv + 1e-15f), red, c);
  if (c == 0) entpart[n] = esum;
}

// fused: xp (64 blk) | adj_s (128 blk) | link (256 blk); 256 thr each
__global__ __launch_bounds__(256) void fuse1_kernel(
    const float* __restrict__ s, const float* __restrict__ x1,
    const float* __restrict__ adj, const float* __restrict__ st,
    float* __restrict__ xp, float* __restrict__ t, float* __restrict__ linkpart)
{
  __shared__ float sn[128]; __shared__ float red[256];
  int b = blockIdx.x, tid = threadIdx.x;
  if (b < 64){
    int cc = b*2 + (tid >> 7), f = tid & 127;
    float acc = 0.f;
    for (int n = 0; n < NN1; ++n) acc += s[n*128+cc] * x1[n*128+f];
    xp[cc*128+f] = acc;
  } else if (b < 192){
    int n = (b-64)*2 + (tid >> 7), c = tid & 127;
    float acc = 0.f;
    for (int m = 0; m < NN1; ++m){
      float a = adj[n*NN1+m];
      if (a != 0.f) acc += a * s[m*128+c];
    }
    t[n*128+c] = acc;
  } else {
    int n = b - 192, m = tid;
    if (m < 128) sn[m] = s[n*128+m];
    __syncthreads();
    float dot = 0.f;
    for (int c = 0; c < 128; ++c) dot += sn[c]*st[c*NN1 + m];
    float v = adj[n*NN1+m] - dot;
    float part = block_sum<256>(v*v, red, m);
    if (m == 0) linkpart[n] = part;
  }
}

__global__ __launch_bounds__(128) void adjp_kernel(const float* __restrict__ s,
    const float* __restrict__ t, float* __restrict__ adjp){
  int cc = blockIdx.x, d = threadIdx.x;
  float acc = 0.f;
  for (int n = 0; n < NN1; ++n) acc += s[n*128+cc] * t[n*128+d];
  adjp[cc*128+d] = acc;
}

__global__ __launch_bounds__(128) void binarize_kernel(const float* __restrict__ adjp,
    float* __restrict__ edge_out, float* __restrict__ ei2_out, int* __restrict__ cols){
  __shared__ float red[128]; __shared__ int redi[128];
  int i = blockIdx.x, j = threadIdx.x;
  float v = adjp[i*128+j];
  float mx = block_max<128>(v, red, j);
  edge_out[i*128+j] = (v == mx) ? 1.0f : 0.0f;
  int cand = (v == mx) ? j : (1 << 30);
  int cmin = block_min_int<128>(cand, redi, j);
  if (j == 0){
    cols[i] = cmin;
    ei2_out[i] = (float)i;
    ei2_out[128 + i] = (float)cmin;
  }
}

__global__ __launch_bounds__(128) void sage3_agg_kernel(const float* __restrict__ xp,
    const int* __restrict__ cols, float* __restrict__ aggn3){
  int d = blockIdx.x, f = threadIdx.x;
  float acc = 0.f, c = 0.f;
  for (int i = 0; i < NN2; ++i){
    if (cols[i] == d){ acc += xp[i*128+f]; c += 1.f; }
  }
  aggn3[d*128+f] = acc / fmaxf(c, 1.f);
}

__global__ __launch_bounds__(128) void sage3_out_kernel(const float* __restrict__ aggn3,
    const float* __restrict__ xp,
    const float* __restrict__ wl3, const float* __restrict__ bl3, const float* __restrict__ wr3,
    float* __restrict__ nodes_out)
{
  __shared__ float red[128];
  int n = blockIdx.x, k = threadIdx.x;
  float ag = aggn3[n*128+k];
  float xv = xp[n*128+k];
  float q0 = block_sum<128>(ag*wl3[k]     + xv*wr3[k],     red, k);
  float q1 = block_sum<128>(ag*wl3[128+k] + xv*wr3[128+k], red, k);
  if (k == 0){
    float p0 = q0 + bl3[0], p1 = q1 + bl3[1];
    float nm = fmaxf(sqrtf(p0*p0 + p1*p1), 1e-12f);
    nodes_out[n*2+0] = tanhf(p0/nm);
    nodes_out[n*2+1] = tanhf(p1/nm);
  }
}

__global__ __launch_bounds__(256) void finalize_kernel(const float* __restrict__ linkpart,
    const float* __restrict__ entpart, float* __restrict__ d_out)
{
  __shared__ float red[256];
  int t = threadIdx.x;
  float ls = block_sum<256>(linkpart[t], red, t);
  float es = block_sum<256>(entpart[t], red, t);
  float v0 = 0.f, v1 = 0.f;
  if (t < 128){ v0 = d_out[4 + t*2 + 0]; v1 = d_out[4 + t*2 + 1]; }
  float s0 = block_sum<256>(v0, red, t);
  float s1 = block_sum<256>(v1, red, t);
  if (t == 0){
    d_out[0] = s0;
    d_out[1] = s1;
    d_out[2] = sqrtf(ls)/65536.0f + sqrtf(16256.0f)/16384.0f;  // ll1 + ll2(const)
    d_out[3] = es/256.0f;                                      // el1 + el2(=0)
  }
}

extern "C" void kernel_launch(void* const* d_in, const int* in_sizes, int n_in,
                              void* d_out_v, int out_size, void* d_ws, size_t ws_size,
                              hipStream_t stream)
{
  (void)in_sizes; (void)n_in; (void)out_size; (void)ws_size;
  const float* input = (const float*)d_in[0];
  const int*   ei    = (const int*)  d_in[1];
  const float* w1 = (const float*)d_in[2];  const float* b1 = (const float*)d_in[3];
  const float* w2 = (const float*)d_in[4];  const float* b2 = (const float*)d_in[5];
  const float* w3 = (const float*)d_in[6];  const float* b3 = (const float*)d_in[7];
  const float* w4 = (const float*)d_in[8];  const float* b4 = (const float*)d_in[9];
  const float* w5 = (const float*)d_in[10]; const float* b5 = (const float*)d_in[11];
  const float* s1wl = (const float*)d_in[12]; const float* s1bl = (const float*)d_in[13];
  const float* s1wr = (const float*)d_in[14];
  const float* s2wl = (const float*)d_in[15]; const float* s2bl = (const float*)d_in[16];
  const float* s2wr = (const float*)d_in[17];
  const float* s3wl = (const float*)d_in[18]; const float* s3bl = (const float*)d_in[19];
  const float* s3wr = (const float*)d_in[20];
  float* d_out = (float*)d_out_v;
  float* ws = (float*)d_ws;

  // Padded buffers [C][H+2][row], row = W+2 padded to x4; interior at +row+1.
  // P1: 32x258x260  P2: 64x130x132  P3: 128x66x68  P4: 256x34x36
  float* P1  = ws;                    // 2,146,560
  float* P2  = ws + 2146560;          // 1,098,240 (graph scratch aliases after L3)
  float* P3  = ws + 3244800;          //   574,464
  float* P4  = ws + 3819264;          //   313,344
  float* org = ws + 4132608;          //    65,536
  float* P0  = ws + 4198144;          // 1,326,120
  float* wt  = ws + 5524264;          //   131,072 (transposed sage weights; own region)
  float* st  = ws + 5655336;          //    32,768 (s^T)  -> total 5,688,104 = 22.8 MB
  float* PART = P1;                   // split-K partials (2,097,152; P1 dead after L2)

  // graph scratch (after convs) aliases P2 region
  float* G        = P2;
  float* adj1     = G;                   // 65,536
  float* cnt      = G + 65536;           // 256
  float* aggn3    = G + 65792;           // 16,384
  float* aggn     = G + 82176;           // 65,536
  float* x1       = G + 147712;          // 32,768
  float* s        = G + 180480;          // 32,768
  float* t        = G + 213248;          // 32,768
  float* xp       = G + 246016;          // 16,384
  float* adjp     = G + 262400;          // 16,384
  int*   cols     = (int*)(G + 278784);  // 128
  float* linkpart = G + 278912;          // 256
  float* entpart  = G + 279168;          // 256

  const int p1r = 260, p1c = 258*260;
  const int p2r = 132, p2c = 130*132;
  const int p3r = 68,  p3c = 66*68;
  const int p4r = 36,  p4c = 34*36;
  const int p0r = 516, p0c = 514*516;

  // zero padded buffers + P0 (borders must be 0; interiors overwritten each call)
  hipMemsetAsync(ws, 0, (size_t)5524264*sizeof(float), stream);
  // prep: pad input (1280 blk) + transpose sage weights (512 blk)
  prep_kernel<<<dim3(1792), 256, 0, stream>>>(input, P0, s1wl, s1wr, s2wl, s2wr, wt);

  // L1: 5->32 @512   CG2  x 32x32 tiles -> 2048 blocks (CHUNK=5, NCH=1)
  conv10<5,32,5,1>    <<<dim3(64,32,1), 256, 0, stream>>>(P0, w1, b1, P1+p1r+1, 512,512, p0r,p0c, p1r,p1c);
  // L2: 32->64 @256  CG4  x 16x16 tiles -> 1024 blocks
  conv10<32,64,8,1>   <<<dim3(64,16,1), 256, 0, stream>>>(P1, w2, b2, P2+p2r+1, 256,256, p1r,p1c, p2r,p2c);
  // L3: 64->128 @128 CG8  x 8x8 tiles  -> 512 blocks
  conv10<64,128,8,1>  <<<dim3(64,8,1),  256, 0, stream>>>(P2, w3, b3, P3+p3r+1, 128,128, p2r,p2c, p3r,p3c);
  // L4: 128->256 @64 CG16 x 4x4 tiles x sk2 -> 512 blocks; PART 2x256x64x64
  conv10<128,256,8,2> <<<dim3(64,4,2),  256, 0, stream>>>(P3, w4, b4, PART, 64,64, p3r,p3c, 0,0);
  reduce_pool<2>      <<<dim3(1024),    256, 0, stream>>>(PART, b4, P4+p4r+1, 256, 64,64, p4r,p4c);
  // L5: 256->256 @32 CG16 x 2x2 tiles x sk8 -> 512 blocks; PART 8x256x32x32
  conv10<256,256,8,8> <<<dim3(32,2,8),  256, 0, stream>>>(P4, w5, b5, PART, 32,32, p4r,p4c, 0,0);
  reduce_pool<8>      <<<dim3(256),     256, 0, stream>>>(PART, b5, org, 256, 32,32, 16,256);

  // graph tail (P2 region now reusable as scratch)
  hipMemsetAsync(adj1, 0, (65536 + 256)*sizeof(float), stream);
  build_adj_kernel<<<dim3(16),  256, 0, stream>>>(ei, adj1, cnt);
  agg_kernel      <<<dim3(256), 256, 0, stream>>>(adj1, cnt, org, aggn);
  sage12_kernel   <<<dim3(256), 128, 0, stream>>>(aggn, org, wt, s1bl, wt+32768,
                                                  wt+65536, s2bl, wt+98304, x1, s, st, entpart);
  fuse1_kernel    <<<dim3(448), 256, 0, stream>>>(s, x1, adj1, st, xp, t, linkpart);
  adjp_kernel     <<<dim3(128), 128, 0, stream>>>(s, t, adjp);
  binarize_kernel <<<dim3(128), 128, 0, stream>>>(adjp, d_out + 260, d_out + 16644, cols);
  sage3_agg_kernel<<<dim3(128), 128, 0, stream>>>(xp, cols, aggn3);
  sage3_out_kernel<<<dim3(128), 128, 0, stream>>>(aggn3, xp, s3wl, s3bl, s3wr, d_out + 4);
  finalize_kernel <<<dim3(1),   256, 0, stream>>>(linkpart, entpart, d_out);
}

// Round 11
// 266.533 us; speedup vs baseline: 1.9256x; 1.9256x over previous
//
#include <hip/hip_runtime.h>
#include <hip/hip_bf16.h>
#include <math.h>

#define N_EDGES 4096
#define NN1 256
#define NN2 128

typedef short v8s __attribute__((ext_vector_type(8)));
typedef float v4f __attribute__((ext_vector_type(4)));

__device__ inline unsigned short f2b(float f){
  union { __hip_bfloat16 h; unsigned short u; } cv;
  cv.h = __float2bfloat16(f);
  return cv.u;
}

// ---------------- reduction helpers ----------------
template<int NT>
__device__ inline float block_sum(float v, float* red, int t){
  red[t] = v; __syncthreads();
  #pragma unroll
  for (int st = NT/2; st > 0; st >>= 1){
    if (t < st) red[t] += red[t+st];
    __syncthreads();
  }
  float r = red[0]; __syncthreads();
  return r;
}
template<int NT>
__device__ inline float block_max(float v, float* red, int t){
  red[t] = v; __syncthreads();
  #pragma unroll
  for (int st = NT/2; st > 0; st >>= 1){
    if (t < st) red[t] = fmaxf(red[t], red[t+st]);
    __syncthreads();
  }
  float r = red[0]; __syncthreads();
  return r;
}
template<int NT>
__device__ inline int block_min_int(int v, int* red, int t){
  red[t] = v; __syncthreads();
  #pragma unroll
  for (int st = NT/2; st > 0; st >>= 1){
    if (t < st) red[t] = min(red[t], red[t+st]);
    __syncthreads();
  }
  int r = red[0]; __syncthreads();
  return r;
}

// ---------------- conv3x3(SAME) via bf16 MFMA implicit GEMM ----------------
// Activations: bf16 slab-packed [C/8][y][x][8ci], zero-bordered (pitch in_row px,
// slab stride in_slab bf16). Weights: bf16 [k][cout][cin] (pre-transposed).
// Block 256 thr = 4 waves; block computes 16x16 conv region for 32 couts
// (wave wv: cout-tile cot=wv>>1, row-half wp=wv&1 -> 8 N-tiles=rows).
// Per tap k: A-frag = W[k][cot*16+lane&15][(lane>>4)*8..+7] (one b128);
// B-frag = X[(lane>>4) slab][row t+ky][px lane&15 + kx][8ci] (one b128);
// acc[t] f32x4 via mfma_f32_16x16x32_bf16 (C: col=lane&15=px, row=(lane>>4)*4+r=co).
// Epilogue: pool2x2 (rows in-register, cols via shfl_xor 1) + bias + relu ->
// bf16 slab-packed out (or f32 org for the last layer).
template<int CHUNKS, int COUT, int CIN, int SSLABS, int BSTR, int OUTF32>
__global__ __launch_bounds__(256) void conv_mfma(
    const unsigned short* __restrict__ in, const unsigned short* __restrict__ wb,
    const float* __restrict__ bias, unsigned short* __restrict__ outb,
    float* __restrict__ outf,
    int in_row, int in_slab, int out_row, int out_slab)
{
  constexpr int CG = COUT/32;
  __shared__ unsigned short tileb[SSLABS*2600];   // SSLABS slabs x 18x18 px x 8ci (+8 pad)
  __shared__ unsigned short wldsb[9*32*40];       // [k][co32][ci32 pad40]

  const int cg = blockIdx.x % CG, bx = blockIdx.x / CG, by = blockIdx.y;
  const int tid = threadIdx.x, lane = tid & 63, wv = tid >> 6;
  const int cot = wv >> 1, wp = wv & 1;
  const int ml = lane & 15, g = lane >> 4;

  v4f acc[8];
  #pragma unroll
  for (int t = 0; t < 8; ++t) acc[t] = (v4f){0.f,0.f,0.f,0.f};

  for (int cb = 0; cb < CHUNKS; ++cb){
    if (cb) __syncthreads();
    // stage activation tile: SSLABS x 18 rows x 18 px, 16B per px-slab
    for (int j = tid; j < SSLABS*324; j += 256){
      int s = j / 324, rem = j - s*324;
      int row = rem / 18, px = rem - row*18;
      int gidx = (cb*SSLABS + s)*in_slab + ((by*16 + row)*in_row + bx*16 + px)*8;
      *(v8s*)&tileb[s*2600 + (row*18+px)*8] = *(const v8s*)&in[gidx];
    }
    // stage weights: 9 taps x 32 co x 4 ci-octets
    for (int j = tid; j < 1152; j += 256){
      int k = j >> 7, rem = j & 127;
      int co = rem >> 2, q = rem & 3;
      int gw = (k*COUT + cg*32 + co)*CIN + cb*32 + q*8;
      *(v8s*)&wldsb[(k*32+co)*40 + q*8] = *(const v8s*)&wb[gw];
    }
    __syncthreads();

    #pragma unroll
    for (int k9 = 0; k9 < 9; ++k9){
      const int ky = k9/3, kx = k9 - 3*(k9/3);
      v8s a = *(const v8s*)&wldsb[(k9*32 + cot*16 + ml)*40 + g*8];
      #pragma unroll
      for (int tt = 0; tt < 8; ++tt){
        int t = wp*8 + tt;
        v8s b = *(const v8s*)&tileb[g*BSTR + ((t+ky)*18 + kx + ml)*8];
        acc[tt] = __builtin_amdgcn_mfma_f32_16x16x32_bf16(a, b, acc[tt], 0, 0, 0);
      }
    }
  }

  // epilogue: maxpool2x2 + bias + relu
  const int cob = cg*32 + cot*16 + g*4;
  float b4[4] = {bias[cob], bias[cob+1], bias[cob+2], bias[cob+3]};
  #pragma unroll
  for (int tp = 0; tp < 4; ++tp){
    float m[4];
    #pragma unroll
    for (int r = 0; r < 4; ++r){
      float v = fmaxf(acc[2*tp][r], acc[2*tp+1][r]);   // vertical pair (rows)
      float o = __shfl_xor(v, 1);                      // horizontal pair (cols)
      m[r] = fmaxf(fmaxf(v, o) + b4[r], 0.f);
    }
    if ((lane & 1) == 0){
      int gy = by*8 + wp*4 + tp, gx = bx*8 + (ml >> 1);
      if (OUTF32){
        #pragma unroll
        for (int r = 0; r < 4; ++r)
          outf[(cob + r)*256 + gy*16 + gx] = m[r];
      } else {
        unsigned int u0 = (unsigned)f2b(m[0]) | ((unsigned)f2b(m[1]) << 16);
        unsigned int u1 = (unsigned)f2b(m[2]) | ((unsigned)f2b(m[3]) << 16);
        int slabo = cob >> 3, sub = (g & 1)*4;
        size_t idx = (size_t)slabo*out_slab + (size_t)((gy+1)*out_row + gx+1)*8 + sub;
        *(uint2*)(outb + idx) = make_uint2(u0, u1);
      }
    }
  }
}

// ---------------- prep: pad+pack input to bf16 slabs, transpose+cvt conv weights,
// ---------------- transpose sage weights ----------------
__global__ __launch_bounds__(256) void prep_kernel(
    const float* __restrict__ src, unsigned short* __restrict__ p0b,
    const float* __restrict__ w1, const float* __restrict__ w2,
    const float* __restrict__ w3, const float* __restrict__ w4,
    const float* __restrict__ w5, unsigned short* __restrict__ wbb,
    const float* __restrict__ a, const float* __restrict__ b2,
    const float* __restrict__ c2, const float* __restrict__ d2,
    float* __restrict__ o)
{
  int b = blockIdx.x, tid = threadIdx.x;
  if (b < 1280){
    // input 5x512x512 f32 -> P0b [1 slab][514][516][8] bf16 (ci 5..7 stay 0)
    int idx = b*256 + tid;
    int c = idx >> 16, rem = idx & 65535, y = rem >> 7, xq = rem & 127;
    float4 v = *(const float4*)&src[c*262144 + y*512 + 4*xq];
    float vv[4] = {v.x, v.y, v.z, v.w};
    #pragma unroll
    for (int i = 0; i < 4; ++i)
      p0b[((y+1)*516 + (4*xq+i+1))*8 + c] = f2b(vv[i]);
  } else if (b < 1708){
    // conv weights -> bf16 [k][co][ci]; L1 padded to ci32 with zeros
    int j = (b-1280)*256 + tid;   // 0..109567
    int co, ci, CO, CIl, CIsrc, dst; const float* w;
    if (j < 1024)      { co=j>>5;        ci=j&31;        w=w1; CIsrc=5;   CO=32;  CIl=32;  dst=0; }
    else if (j < 3072) { int q=j-1024;   co=q>>5;  ci=q&31;  w=w2; CIsrc=32;  CO=64;  CIl=32;  dst=9216; }
    else if (j < 11264){ int q=j-3072;   co=q>>6;  ci=q&63;  w=w3; CIsrc=64;  CO=128; CIl=64;  dst=27648; }
    else if (j < 44032){ int q=j-11264;  co=q>>7;  ci=q&127; w=w4; CIsrc=128; CO=256; CIl=128; dst=101376; }
    else               { int q=j-44032;  co=q>>8;  ci=q&255; w=w5; CIsrc=256; CO=256; CIl=256; dst=396288; }
    #pragma unroll
    for (int k = 0; k < 9; ++k){
      float val = (ci < CIsrc) ? w[(co*CIsrc + ci)*9 + k] : 0.f;
      wbb[dst + (k*CO + co)*CIl + ci] = f2b(val);
    }
  } else {
    // sage weight transpose [128][256] -> [256][128] x4
    int idx = (b-1708)*256 + tid;
    int m = idx >> 15, rem = idx & 32767, k = rem >> 7, cc = rem & 127;
    const float* sp = (m==0)?a:(m==1)?b2:(m==2)?c2:d2;
    o[m*32768 + k*128 + cc] = sp[cc*256 + k];
  }
}

// ---------------- graph kernels (unchanged, fp32) ----------------
__global__ void build_adj_kernel(const int* __restrict__ ei, float* adj, float* cnt){
  int e = blockIdx.x*256 + threadIdx.x;
  if (e < N_EDGES){
    int s = ei[e], d = ei[N_EDGES + e];
    atomicAdd(&adj[s*NN1 + d], 1.0f);   // integer-valued -> order independent
    atomicAdd(&cnt[d], 1.0f);
  }
}

__global__ __launch_bounds__(256) void agg_kernel(const float* __restrict__ adj,
    const float* __restrict__ cnt, const float* __restrict__ org, float* __restrict__ aggn){
  int d = blockIdx.x, j = threadIdx.x;
  float acc = 0.f;
  for (int s = 0; s < NN1; ++s){
    float a = adj[s*NN1 + d];
    if (a != 0.f) acc += a * org[s*NN1 + j];
  }
  aggn[d*NN1 + j] = acc / fmaxf(cnt[d], 1.0f);
}

__global__ __launch_bounds__(128) void sage12_kernel(
    const float* __restrict__ aggn, const float* __restrict__ org,
    const float* __restrict__ wl1t, const float* __restrict__ bl1, const float* __restrict__ wr1t,
    const float* __restrict__ wl2t, const float* __restrict__ bl2, const float* __restrict__ wr2t,
    float* __restrict__ x1, float* __restrict__ s_out, float* __restrict__ st,
    float* __restrict__ entpart)
{
  __shared__ float sa[NN1], so[NN1], red[128];
  int n = blockIdx.x, c = threadIdx.x;
  for (int k = c; k < NN1; k += 128){ sa[k] = aggn[n*NN1+k]; so[k] = org[n*NN1+k]; }
  __syncthreads();
  float p1 = bl1[c], p2 = bl2[c];
  for (int k = 0; k < NN1; ++k){
    float av = sa[k], ov = so[k];
    p1 += av*wl1t[k*128+c] + ov*wr1t[k*128+c];
    p2 += av*wl2t[k*128+c] + ov*wr2t[k*128+c];
  }
  float n1s = block_sum<128>(p1*p1, red, c);
  x1[n*128 + c] = p1 / fmaxf(sqrtf(n1s), 1e-12f);
  float n2s = block_sum<128>(p2*p2, red, c);
  float p2n = p2 / fmaxf(sqrtf(n2s), 1e-12f);
  float mx = block_max<128>(p2n, red, c);
  float ev = expf(p2n - mx);
  float ssum = block_sum<128>(ev, red, c);
  float sv = ev / ssum;
  s_out[n*128 + c] = sv;
  st[c*NN1 + n] = sv;
  float esum = block_sum<128>(-sv * logf(sv + 1e-15f), red, c);
  if (c == 0) entpart[n] = esum;
}

// fused: xp (64 blk) | adj_s (128 blk) | link (256 blk)
__global__ __launch_bounds__(256) void fuse1_kernel(
    const float* __restrict__ s, const float* __restrict__ x1,
    const float* __restrict__ adj, const float* __restrict__ st,
    float* __restrict__ xp, float* __restrict__ t, float* __restrict__ linkpart)
{
  __shared__ float sn[128]; __shared__ float red[256];
  int b = blockIdx.x, tid = threadIdx.x;
  if (b < 64){
    int cc = b*2 + (tid >> 7), f = tid & 127;
    float acc = 0.f;
    for (int n = 0; n < NN1; ++n) acc += s[n*128+cc] * x1[n*128+f];
    xp[cc*128+f] = acc;
  } else if (b < 192){
    int n = (b-64)*2 + (tid >> 7), c = tid & 127;
    float acc = 0.f;
    for (int m = 0; m < NN1; ++m){
      float a = adj[n*NN1+m];
      if (a != 0.f) acc += a * s[m*128+c];
    }
    t[n*128+c] = acc;
  } else {
    int n = b - 192, m = tid;
    if (m < 128) sn[m] = s[n*128+m];
    __syncthreads();
    float dot = 0.f;
    for (int c = 0; c < 128; ++c) dot += sn[c]*st[c*NN1 + m];
    float v = adj[n*NN1+m] - dot;
    float part = block_sum<256>(v*v, red, m);
    if (m == 0) linkpart[n] = part;
  }
}

__global__ __launch_bounds__(128) void adjp_kernel(const float* __restrict__ s,
    const float* __restrict__ t, float* __restrict__ adjp){
  int cc = blockIdx.x, d = threadIdx.x;
  float acc = 0.f;
  for (int n = 0; n < NN1; ++n) acc += s[n*128+cc] * t[n*128+d];
  adjp[cc*128+d] = acc;
}

__global__ __launch_bounds__(128) void binarize_kernel(const float* __restrict__ adjp,
    float* __restrict__ edge_out, float* __restrict__ ei2_out, int* __restrict__ cols){
  __shared__ float red[128]; __shared__ int redi[128];
  int i = blockIdx.x, j = threadIdx.x;
  float v = adjp[i*128+j];
  float mx = block_max<128>(v, red, j);
  edge_out[i*128+j] = (v == mx) ? 1.0f : 0.0f;
  int cand = (v == mx) ? j : (1 << 30);
  int cmin = block_min_int<128>(cand, redi, j);
  if (j == 0){
    cols[i] = cmin;
    ei2_out[i] = (float)i;
    ei2_out[128 + i] = (float)cmin;
  }
}

__global__ __launch_bounds__(128) void sage3_agg_kernel(const float* __restrict__ xp,
    const int* __restrict__ cols, float* __restrict__ aggn3){
  int d = blockIdx.x, f = threadIdx.x;
  float acc = 0.f, c = 0.f;
  for (int i = 0; i < NN2; ++i){
    if (cols[i] == d){ acc += xp[i*128+f]; c += 1.f; }
  }
  aggn3[d*128+f] = acc / fmaxf(c, 1.f);
}

__global__ __launch_bounds__(128) void sage3_out_kernel(const float* __restrict__ aggn3,
    const float* __restrict__ xp,
    const float* __restrict__ wl3, const float* __restrict__ bl3, const float* __restrict__ wr3,
    float* __restrict__ nodes_out)
{
  __shared__ float red[128];
  int n = blockIdx.x, k = threadIdx.x;
  float ag = aggn3[n*128+k];
  float xv = xp[n*128+k];
  float q0 = block_sum<128>(ag*wl3[k]     + xv*wr3[k],     red, k);
  float q1 = block_sum<128>(ag*wl3[128+k] + xv*wr3[128+k], red, k);
  if (k == 0){
    float p0 = q0 + bl3[0], p1 = q1 + bl3[1];
    float nm = fmaxf(sqrtf(p0*p0 + p1*p1), 1e-12f);
    nodes_out[n*2+0] = tanhf(p0/nm);
    nodes_out[n*2+1] = tanhf(p1/nm);
  }
}

__global__ __launch_bounds__(256) void finalize_kernel(const float* __restrict__ linkpart,
    const float* __restrict__ entpart, float* __restrict__ d_out)
{
  __shared__ float red[256];
  int t = threadIdx.x;
  float ls = block_sum<256>(linkpart[t], red, t);
  float es = block_sum<256>(entpart[t], red, t);
  float v0 = 0.f, v1 = 0.f;
  if (t < 128){ v0 = d_out[4 + t*2 + 0]; v1 = d_out[4 + t*2 + 1]; }
  float s0 = block_sum<256>(v0, red, t);
  float s1 = block_sum<256>(v1, red, t);
  if (t == 0){
    d_out[0] = s0;
    d_out[1] = s1;
    d_out[2] = sqrtf(ls)/65536.0f + sqrtf(16256.0f)/16384.0f;  // ll1 + ll2(const)
    d_out[3] = es/256.0f;                                      // el1 + el2(=0)
  }
}

extern "C" void kernel_launch(void* const* d_in, const int* in_sizes, int n_in,
                              void* d_out_v, int out_size, void* d_ws, size_t ws_size,
                              hipStream_t stream)
{
  (void)in_sizes; (void)n_in; (void)out_size; (void)ws_size;
  const float* input = (const float*)d_in[0];
  const int*   ei    = (const int*)  d_in[1];
  const float* w1 = (const float*)d_in[2];  const float* b1 = (const float*)d_in[3];
  const float* w2 = (const float*)d_in[4];  const float* b2 = (const float*)d_in[5];
  const float* w3 = (const float*)d_in[6];  const float* b3 = (const float*)d_in[7];
  const float* w4 = (const float*)d_in[8];  const float* b4 = (const float*)d_in[9];
  const float* w5 = (const float*)d_in[10]; const float* b5 = (const float*)d_in[11];
  const float* s1wl = (const float*)d_in[12]; const float* s1bl = (const float*)d_in[13];
  const float* s1wr = (const float*)d_in[14];
  const float* s2wl = (const float*)d_in[15]; const float* s2bl = (const float*)d_in[16];
  const float* s2wr = (const float*)d_in[17];
  const float* s3wl = (const float*)d_in[18]; const float* s3bl = (const float*)d_in[19];
  const float* s3wr = (const float*)d_in[20];
  float* d_out = (float*)d_out_v;
  float* ws = (float*)d_ws;

  // f32-unit offsets (bf16 buffers use 2 bf16 per unit)
  // P0b 1,060,896 | Pb1 1,073,280 | Pb2 549,120 | Pb3 287,232 | Pb4 156,672
  // wb 493,056 | org 65,536 | wt 131,072 | st 32,768 | G 279,424  -> 16.5 MB
  unsigned short* P0b = (unsigned short*)(ws);
  unsigned short* Pb1 = (unsigned short*)(ws + 1060896);
  unsigned short* Pb2 = (unsigned short*)(ws + 2134176);
  unsigned short* Pb3 = (unsigned short*)(ws + 2683296);
  unsigned short* Pb4 = (unsigned short*)(ws + 2970528);
  unsigned short* wb  = (unsigned short*)(ws + 3127200);
  float* org = ws + 3620256;
  float* wt  = ws + 3685792;
  float* st  = ws + 3816864;
  float* G   = ws + 3849632;

  float* adj1     = G;                   // 65,536
  float* cnt      = G + 65536;           // 256
  float* aggn3    = G + 65792;           // 16,384
  float* aggn     = G + 82176;           // 65,536
  float* x1       = G + 147712;          // 32,768
  float* s        = G + 180480;          // 32,768
  float* t        = G + 213248;          // 32,768
  float* xp       = G + 246016;          // 16,384
  float* adjp     = G + 262400;          // 16,384
  int*   cols     = (int*)(G + 278784);  // 128
  float* linkpart = G + 278912;          // 256
  float* entpart  = G + 279168;          // 256

  // zero all bf16 activation buffers (borders must be 0; interiors overwritten)
  hipMemsetAsync(ws, 0, (size_t)3127200*sizeof(float), stream);
  // prep: pack input bf16 (1280) + conv weights bf16 [k][co][ci] (428) + sage wt (512)
  prep_kernel<<<dim3(2220), 256, 0, stream>>>(input, P0b, w1, w2, w3, w4, w5, wb,
                                              s1wl, s1wr, s2wl, s2wr, wt);

  // conv stack (bf16 MFMA):   grid = (W/16 * COUT/32, H/16)
  conv_mfma<1,32,32,1,0,0>      <<<dim3(32,32), 256, 0, stream>>>(P0b, wb,        b1, Pb1, nullptr, 516, 2121792, 260, 536640);
  conv_mfma<1,64,32,4,2600,0>   <<<dim3(32,16), 256, 0, stream>>>(Pb1, wb+9216,   b2, Pb2, nullptr, 260, 536640, 132, 137280);
  conv_mfma<2,128,64,4,2600,0>  <<<dim3(32,8),  256, 0, stream>>>(Pb2, wb+27648,  b3, Pb3, nullptr, 132, 137280, 68,  35904);
  conv_mfma<4,256,128,4,2600,0> <<<dim3(32,4),  256, 0, stream>>>(Pb3, wb+101376, b4, Pb4, nullptr, 68,  35904,  36,  9792);
  conv_mfma<8,256,256,4,2600,1> <<<dim3(16,2),  256, 0, stream>>>(Pb4, wb+396288, b5, nullptr, org, 36,  9792,   0,   0);

  // graph tail (fp32, unchanged)
  hipMemsetAsync(adj1, 0, (65536 + 256)*sizeof(float), stream);
  build_adj_kernel<<<dim3(16),  256, 0, stream>>>(ei, adj1, cnt);
  agg_kernel      <<<dim3(256), 256, 0, stream>>>(adj1, cnt, org, aggn);
  sage12_kernel   <<<dim3(256), 128, 0, stream>>>(aggn, org, wt, s1bl, wt+32768,
                                                  wt+65536, s2bl, wt+98304, x1, s, st, entpart);
  fuse1_kernel    <<<dim3(448), 256, 0, stream>>>(s, x1, adj1, st, xp, t, linkpart);
  adjp_kernel     <<<dim3(128), 128, 0, stream>>>(s, t, adjp);
  binarize_kernel <<<dim3(128), 128, 0, stream>>>(adjp, d_out + 260, d_out + 16644, cols);
  sage3_agg_kernel<<<dim3(128), 128, 0, stream>>>(xp, cols, aggn3);
  sage3_out_kernel<<<dim3(128), 128, 0, stream>>>(aggn3, xp, s3wl, s3bl, s3wr, d_out + 4);
  finalize_kernel <<<dim3(1),   256, 0, stream>>>(linkpart, entpart, d_out);
}

// Round 12
// 220.620 us; speedup vs baseline: 2.3263x; 1.2081x over previous
//
#include <hip/hip_runtime.h>
#include <hip/hip_bf16.h>
#include <math.h>

#define N_EDGES 4096
#define NN1 256
#define NN2 128

typedef short v8s __attribute__((ext_vector_type(8)));
typedef float v4f __attribute__((ext_vector_type(4)));

__device__ inline unsigned short f2b(float f){
  union { __hip_bfloat16 h; unsigned short u; } cv;
  cv.h = __float2bfloat16(f);
  return cv.u;
}

// ---------------- reduction helpers ----------------
template<int NT>
__device__ inline float block_sum(float v, float* red, int t){
  red[t] = v; __syncthreads();
  #pragma unroll
  for (int st = NT/2; st > 0; st >>= 1){
    if (t < st) red[t] += red[t+st];
    __syncthreads();
  }
  float r = red[0]; __syncthreads();
  return r;
}
template<int NT>
__device__ inline float block_max(float v, float* red, int t){
  red[t] = v; __syncthreads();
  #pragma unroll
  for (int st = NT/2; st > 0; st >>= 1){
    if (t < st) red[t] = fmaxf(red[t], red[t+st]);
    __syncthreads();
  }
  float r = red[0]; __syncthreads();
  return r;
}
template<int NT>
__device__ inline int block_min_int(int v, int* red, int t){
  red[t] = v; __syncthreads();
  #pragma unroll
  for (int st = NT/2; st > 0; st >>= 1){
    if (t < st) red[t] = min(red[t], red[t+st]);
    __syncthreads();
  }
  int r = red[0]; __syncthreads();
  return r;
}

// ---------------- conv3x3(SAME) via bf16 MFMA implicit GEMM ----------------
// Activations: bf16 slab-packed [C/8][y][x][8ci], zero-bordered (pitch in_row px,
// slab stride in_slab bf16). Weights: bf16 [k][cout][cin] (pre-transposed).
// Block 256 thr = 4 waves; block computes 16x16 conv region for 32 couts
// (wave wv: cout-tile cot=wv>>1, row-half wp=wv&1 -> 8 N-tiles=rows).
// Per tap k: A-frag = W[k][cot*16+lane&15][(lane>>4)*8..+7] (one b128);
// B-frag = X[(lane>>4) slab][row t+ky][px lane&15 + kx][8ci] (one b128);
// acc[t] f32x4 via mfma_f32_16x16x32_bf16 (C: col=lane&15=px, row=(lane>>4)*4+r=co).
// Epilogue: pool2x2 (rows in-register, cols via shfl_xor 1) + bias + relu ->
// bf16 slab-packed out (or f32 org for the last layer).
template<int CHUNKS, int COUT, int CIN, int SSLABS, int BSTR, int OUTF32>
__global__ __launch_bounds__(256) void conv_mfma(
    const unsigned short* __restrict__ in, const unsigned short* __restrict__ wb,
    const float* __restrict__ bias, unsigned short* __restrict__ outb,
    float* __restrict__ outf,
    int in_row, int in_slab, int out_row, int out_slab)
{
  constexpr int CG = COUT/32;
  __shared__ unsigned short tileb[SSLABS*2600];   // SSLABS slabs x 18x18 px x 8ci (+8 pad)
  __shared__ unsigned short wldsb[9*32*40];       // [k][co32][ci32 pad40]

  const int cg = blockIdx.x % CG, bx = blockIdx.x / CG, by = blockIdx.y;
  const int tid = threadIdx.x, lane = tid & 63, wv = tid >> 6;
  const int cot = wv >> 1, wp = wv & 1;
  const int ml = lane & 15, g = lane >> 4;

  v4f acc[8];
  #pragma unroll
  for (int t = 0; t < 8; ++t) acc[t] = (v4f){0.f,0.f,0.f,0.f};

  for (int cb = 0; cb < CHUNKS; ++cb){
    if (cb) __syncthreads();
    // stage activation tile: SSLABS x 18 rows x 18 px, 16B per px-slab
    for (int j = tid; j < SSLABS*324; j += 256){
      int s = j / 324, rem = j - s*324;
      int row = rem / 18, px = rem - row*18;
      int gidx = (cb*SSLABS + s)*in_slab + ((by*16 + row)*in_row + bx*16 + px)*8;
      *(v8s*)&tileb[s*2600 + (row*18+px)*8] = *(const v8s*)&in[gidx];
    }
    // stage weights: 9 taps x 32 co x 4 ci-octets
    for (int j = tid; j < 1152; j += 256){
      int k = j >> 7, rem = j & 127;
      int co = rem >> 2, q = rem & 3;
      int gw = (k*COUT + cg*32 + co)*CIN + cb*32 + q*8;
      *(v8s*)&wldsb[(k*32+co)*40 + q*8] = *(const v8s*)&wb[gw];
    }
    __syncthreads();

    #pragma unroll
    for (int k9 = 0; k9 < 9; ++k9){
      const int ky = k9/3, kx = k9 - 3*(k9/3);
      v8s a = *(const v8s*)&wldsb[(k9*32 + cot*16 + ml)*40 + g*8];
      #pragma unroll
      for (int tt = 0; tt < 8; ++tt){
        int t = wp*8 + tt;
        v8s b = *(const v8s*)&tileb[g*BSTR + ((t+ky)*18 + kx + ml)*8];
        acc[tt] = __builtin_amdgcn_mfma_f32_16x16x32_bf16(a, b, acc[tt], 0, 0, 0);
      }
    }
  }

  // epilogue: maxpool2x2 + bias + relu
  const int cob = cg*32 + cot*16 + g*4;
  float b4[4] = {bias[cob], bias[cob+1], bias[cob+2], bias[cob+3]};
  #pragma unroll
  for (int tp = 0; tp < 4; ++tp){
    float m[4];
    #pragma unroll
    for (int r = 0; r < 4; ++r){
      float v = fmaxf(acc[2*tp][r], acc[2*tp+1][r]);   // vertical pair (rows)
      float o = __shfl_xor(v, 1);                      // horizontal pair (cols)
      m[r] = fmaxf(fmaxf(v, o) + b4[r], 0.f);
    }
    if ((lane & 1) == 0){
      int gy = by*8 + wp*4 + tp, gx = bx*8 + (ml >> 1);
      if (OUTF32){
        #pragma unroll
        for (int r = 0; r < 4; ++r)
          outf[(cob + r)*256 + gy*16 + gx] = m[r];
      } else {
        unsigned int u0 = (unsigned)f2b(m[0]) | ((unsigned)f2b(m[1]) << 16);
        unsigned int u1 = (unsigned)f2b(m[2]) | ((unsigned)f2b(m[3]) << 16);
        int slabo = cob >> 3, sub = (g & 1)*4;
        size_t idx = (size_t)slabo*out_slab + (size_t)((gy+1)*out_row + gx+1)*8 + sub;
        *(uint2*)(outb + idx) = make_uint2(u0, u1);
      }
    }
  }
}

// ---------------- prep: pad+pack input to bf16 slabs, transpose+cvt conv weights,
// ---------------- transpose sage weights ----------------
__global__ __launch_bounds__(256) void prep_kernel(
    const float* __restrict__ src, unsigned short* __restrict__ p0b,
    const float* __restrict__ w1, const float* __restrict__ w2,
    const float* __restrict__ w3, const float* __restrict__ w4,
    const float* __restrict__ w5, unsigned short* __restrict__ wbb,
    const float* __restrict__ a, const float* __restrict__ b2,
    const float* __restrict__ c2, const float* __restrict__ d2,
    float* __restrict__ o)
{
  int b = blockIdx.x, tid = threadIdx.x;
  if (b < 1024){
    // one pixel/thread: 5 coalesced channel reads, one 16B store
    int idx = b*256 + tid;            // 0..262143
    int y = idx >> 9, x = idx & 511;
    unsigned short v8[8];
    #pragma unroll
    for (int c = 0; c < 5; ++c) v8[c] = f2b(src[c*262144 + y*512 + x]);
    v8[5] = 0; v8[6] = 0; v8[7] = 0;
    *(uint4*)&p0b[((size_t)(y+1)*516 + (x+1))*8] = *(uint4*)v8;
  } else if (b < 1452){
    // conv weights -> bf16 [k][co][ci]; L1 padded to ci32 with zeros
    int j = (b-1024)*256 + tid;   // 0..109567
    int co, ci, CO, CIl, CIsrc, dst; const float* w;
    if (j < 1024)      { co=j>>5;        ci=j&31;        w=w1; CIsrc=5;   CO=32;  CIl=32;  dst=0; }
    else if (j < 3072) { int q=j-1024;   co=q>>5;  ci=q&31;  w=w2; CIsrc=32;  CO=64;  CIl=32;  dst=9216; }
    else if (j < 11264){ int q=j-3072;   co=q>>6;  ci=q&63;  w=w3; CIsrc=64;  CO=128; CIl=64;  dst=27648; }
    else if (j < 44032){ int q=j-11264;  co=q>>7;  ci=q&127; w=w4; CIsrc=128; CO=256; CIl=128; dst=101376; }
    else               { int q=j-44032;  co=q>>8;  ci=q&255; w=w5; CIsrc=256; CO=256; CIl=256; dst=396288; }
    #pragma unroll
    for (int k = 0; k < 9; ++k){
      float val = (ci < CIsrc) ? w[(co*CIsrc + ci)*9 + k] : 0.f;
      wbb[dst + (k*CO + co)*CIl + ci] = f2b(val);
    }
  } else {
    // sage weight transpose [128][256] -> [256][128] x4
    int idx = (b-1452)*256 + tid;
    int m = idx >> 15, rem = idx & 32767, k = rem >> 7, cc = rem & 127;
    const float* sp = (m==0)?a:(m==1)?b2:(m==2)?c2:d2;
    o[m*32768 + k*128 + cc] = sp[cc*256 + k];
  }
}

// ---------------- graph kernels (fp32) ----------------
__global__ void build_adj_kernel(const int* __restrict__ ei, float* adj, float* cnt){
  int e = blockIdx.x*256 + threadIdx.x;
  if (e < N_EDGES){
    int s = ei[e], d = ei[N_EDGES + e];
    atomicAdd(&adj[s*NN1 + d], 1.0f);   // integer-valued -> order independent
    atomicAdd(&cnt[d], 1.0f);
  }
}

// sage12 with FUSED neighbor aggregation: per block n, agg[k] computed in-LDS
// (branch-free: adding a*org where a==0 contributes exact +0 -> same values).
__global__ __launch_bounds__(128) void sage12_kernel(
    const float* __restrict__ adj, const float* __restrict__ cnt,
    const float* __restrict__ org,
    const float* __restrict__ wl1t, const float* __restrict__ bl1, const float* __restrict__ wr1t,
    const float* __restrict__ wl2t, const float* __restrict__ bl2, const float* __restrict__ wr2t,
    float* __restrict__ x1, float* __restrict__ s_out, float* __restrict__ st,
    float* __restrict__ entpart)
{
  __shared__ float sa[NN1], so[NN1], col[NN1], red[128];
  int n = blockIdx.x, c = threadIdx.x;
  for (int k = c; k < NN1; k += 128){
    col[k] = adj[k*NN1 + n];      // adj column (parallel scattered loads)
    so[k]  = org[n*NN1 + k];
  }
  __syncthreads();
  // agg: sa[k] = (sum_s adj[s][n]*org[s][k]) / max(cnt[n],1)
  float a0 = 0.f, a1 = 0.f;
  #pragma unroll 4
  for (int s2 = 0; s2 < NN1; ++s2){
    float av = col[s2];
    a0 += av * org[s2*NN1 + c];
    a1 += av * org[s2*NN1 + c + 128];
  }
  float cd = fmaxf(cnt[n], 1.0f);
  sa[c] = a0 / cd;
  sa[c+128] = a1 / cd;
  __syncthreads();

  float p1 = bl1[c], p2 = bl2[c];
  for (int k = 0; k < NN1; ++k){
    float av = sa[k], ov = so[k];
    p1 += av*wl1t[k*128+c] + ov*wr1t[k*128+c];
    p2 += av*wl2t[k*128+c] + ov*wr2t[k*128+c];
  }
  float n1s = block_sum<128>(p1*p1, red, c);
  x1[n*128 + c] = p1 / fmaxf(sqrtf(n1s), 1e-12f);
  float n2s = block_sum<128>(p2*p2, red, c);
  float p2n = p2 / fmaxf(sqrtf(n2s), 1e-12f);
  float mx = block_max<128>(p2n, red, c);
  float ev = expf(p2n - mx);
  float ssum = block_sum<128>(ev, red, c);
  float sv = ev / ssum;
  s_out[n*128 + c] = sv;
  st[c*NN1 + n] = sv;
  float esum = block_sum<128>(-sv * logf(sv + 1e-15f), red, c);
  if (c == 0) entpart[n] = esum;
}

// fused: xp (64 blk) | adj_s (128 blk) | link (256 blk)
__global__ __launch_bounds__(256) void fuse1_kernel(
    const float* __restrict__ s, const float* __restrict__ x1,
    const float* __restrict__ adj, const float* __restrict__ st,
    float* __restrict__ xp, float* __restrict__ t, float* __restrict__ linkpart)
{
  __shared__ float sn[128]; __shared__ float red[256];
  int b = blockIdx.x, tid = threadIdx.x;
  if (b < 64){
    int cc = b*2 + (tid >> 7), f = tid & 127;
    float acc = 0.f;
    for (int n = 0; n < NN1; ++n) acc += s[n*128+cc] * x1[n*128+f];
    xp[cc*128+f] = acc;
  } else if (b < 192){
    int n = (b-64)*2 + (tid >> 7), c = tid & 127;
    float acc = 0.f;
    for (int m = 0; m < NN1; ++m){
      float a = adj[n*NN1+m];
      if (a != 0.f) acc += a * s[m*128+c];
    }
    t[n*128+c] = acc;
  } else {
    int n = b - 192, m = tid;
    if (m < 128) sn[m] = s[n*128+m];
    __syncthreads();
    float dot = 0.f;
    for (int c = 0; c < 128; ++c) dot += sn[c]*st[c*NN1 + m];
    float v = adj[n*NN1+m] - dot;
    float part = block_sum<256>(v*v, red, m);
    if (m == 0) linkpart[n] = part;
  }
}

__global__ __launch_bounds__(128) void adjp_kernel(const float* __restrict__ s,
    const float* __restrict__ t, float* __restrict__ adjp){
  int cc = blockIdx.x, d = threadIdx.x;
  float acc = 0.f;
  for (int n = 0; n < NN1; ++n) acc += s[n*128+cc] * t[n*128+d];
  adjp[cc*128+d] = acc;
}

__global__ __launch_bounds__(128) void binarize_kernel(const float* __restrict__ adjp,
    float* __restrict__ edge_out, float* __restrict__ ei2_out, int* __restrict__ cols){
  __shared__ float red[128]; __shared__ int redi[128];
  int i = blockIdx.x, j = threadIdx.x;
  float v = adjp[i*128+j];
  float mx = block_max<128>(v, red, j);
  edge_out[i*128+j] = (v == mx) ? 1.0f : 0.0f;
  int cand = (v == mx) ? j : (1 << 30);
  int cmin = block_min_int<128>(cand, redi, j);
  if (j == 0){
    cols[i] = cmin;
    ei2_out[i] = (float)i;
    ei2_out[128 + i] = (float)cmin;
  }
}

__global__ __launch_bounds__(128) void sage3_agg_kernel(const float* __restrict__ xp,
    const int* __restrict__ cols, float* __restrict__ aggn3){
  int d = blockIdx.x, f = threadIdx.x;
  float acc = 0.f, c = 0.f;
  for (int i = 0; i < NN2; ++i){
    if (cols[i] == d){ acc += xp[i*128+f]; c += 1.f; }
  }
  aggn3[d*128+f] = acc / fmaxf(c, 1.f);
}

__global__ __launch_bounds__(128) void sage3_out_kernel(const float* __restrict__ aggn3,
    const float* __restrict__ xp,
    const float* __restrict__ wl3, const float* __restrict__ bl3, const float* __restrict__ wr3,
    float* __restrict__ nodes_out)
{
  __shared__ float red[128];
  int n = blockIdx.x, k = threadIdx.x;
  float ag = aggn3[n*128+k];
  float xv = xp[n*128+k];
  float q0 = block_sum<128>(ag*wl3[k]     + xv*wr3[k],     red, k);
  float q1 = block_sum<128>(ag*wl3[128+k] + xv*wr3[128+k], red, k);
  if (k == 0){
    float p0 = q0 + bl3[0], p1 = q1 + bl3[1];
    float nm = fmaxf(sqrtf(p0*p0 + p1*p1), 1e-12f);
    nodes_out[n*2+0] = tanhf(p0/nm);
    nodes_out[n*2+1] = tanhf(p1/nm);
  }
}

__global__ __launch_bounds__(256) void finalize_kernel(const float* __restrict__ linkpart,
    const float* __restrict__ entpart, float* __restrict__ d_out)
{
  __shared__ float red[256];
  int t = threadIdx.x;
  float ls = block_sum<256>(linkpart[t], red, t);
  float es = block_sum<256>(entpart[t], red, t);
  float v0 = 0.f, v1 = 0.f;
  if (t < 128){ v0 = d_out[4 + t*2 + 0]; v1 = d_out[4 + t*2 + 1]; }
  float s0 = block_sum<256>(v0, red, t);
  float s1 = block_sum<256>(v1, red, t);
  if (t == 0){
    d_out[0] = s0;
    d_out[1] = s1;
    d_out[2] = sqrtf(ls)/65536.0f + sqrtf(16256.0f)/16384.0f;  // ll1 + ll2(const)
    d_out[3] = es/256.0f;                                      // el1 + el2(=0)
  }
}

extern "C" void kernel_launch(void* const* d_in, const int* in_sizes, int n_in,
                              void* d_out_v, int out_size, void* d_ws, size_t ws_size,
                              hipStream_t stream)
{
  (void)in_sizes; (void)n_in; (void)out_size; (void)ws_size;
  const float* input = (const float*)d_in[0];
  const int*   ei    = (const int*)  d_in[1];
  const float* w1 = (const float*)d_in[2];  const float* b1 = (const float*)d_in[3];
  const float* w2 = (const float*)d_in[4];  const float* b2 = (const float*)d_in[5];
  const float* w3 = (const float*)d_in[6];  const float* b3 = (const float*)d_in[7];
  const float* w4 = (const float*)d_in[8];  const float* b4 = (const float*)d_in[9];
  const float* w5 = (const float*)d_in[10]; const float* b5 = (const float*)d_in[11];
  const float* s1wl = (const float*)d_in[12]; const float* s1bl = (const float*)d_in[13];
  const float* s1wr = (const float*)d_in[14];
  const float* s2wl = (const float*)d_in[15]; const float* s2bl = (const float*)d_in[16];
  const float* s2wr = (const float*)d_in[17];
  const float* s3wl = (const float*)d_in[18]; const float* s3bl = (const float*)d_in[19];
  const float* s3wr = (const float*)d_in[20];
  float* d_out = (float*)d_out_v;
  float* ws = (float*)d_ws;

  // f32-unit offsets (bf16 buffers use 2 bf16 per unit)
  unsigned short* P0b = (unsigned short*)(ws);
  unsigned short* Pb1 = (unsigned short*)(ws + 1060896);
  unsigned short* Pb2 = (unsigned short*)(ws + 2134176);
  unsigned short* Pb3 = (unsigned short*)(ws + 2683296);
  unsigned short* Pb4 = (unsigned short*)(ws + 2970528);
  unsigned short* wb  = (unsigned short*)(ws + 3127200);
  float* org = ws + 3620256;
  float* wt  = ws + 3685792;
  float* st  = ws + 3816864;
  float* G   = ws + 3849632;

  float* adj1     = G;                   // 65,536
  float* cnt      = G + 65536;           // 256
  float* aggn3    = G + 65792;           // 16,384
  float* x1       = G + 147712;          // 32,768
  float* s        = G + 180480;          // 32,768
  float* t        = G + 213248;          // 32,768
  float* xp       = G + 246016;          // 16,384
  float* adjp     = G + 262400;          // 16,384
  int*   cols     = (int*)(G + 278784);  // 128
  float* linkpart = G + 278912;          // 256
  float* entpart  = G + 279168;          // 256

  // zero all bf16 activation buffers (borders must be 0; interiors overwritten)
  hipMemsetAsync(ws, 0, (size_t)3127200*sizeof(float), stream);
  // prep: pack input bf16 (1024) + conv weights bf16 [k][co][ci] (428) + sage wt (512)
  prep_kernel<<<dim3(1964), 256, 0, stream>>>(input, P0b, w1, w2, w3, w4, w5, wb,
                                              s1wl, s1wr, s2wl, s2wr, wt);

  // conv stack (bf16 MFMA):   grid = (W/16 * COUT/32, H/16)
  conv_mfma<1,32,32,1,0,0>      <<<dim3(32,32), 256, 0, stream>>>(P0b, wb,        b1, Pb1, nullptr, 516, 2121792, 260, 536640);
  conv_mfma<1,64,32,4,2600,0>   <<<dim3(32,16), 256, 0, stream>>>(Pb1, wb+9216,   b2, Pb2, nullptr, 260, 536640, 132, 137280);
  conv_mfma<2,128,64,4,2600,0>  <<<dim3(32,8),  256, 0, stream>>>(Pb2, wb+27648,  b3, Pb3, nullptr, 132, 137280, 68,  35904);
  conv_mfma<4,256,128,4,2600,0> <<<dim3(32,4),  256, 0, stream>>>(Pb3, wb+101376, b4, Pb4, nullptr, 68,  35904,  36,  9792);
  conv_mfma<8,256,256,4,2600,1> <<<dim3(16,2),  256, 0, stream>>>(Pb4, wb+396288, b5, nullptr, org, 36,  9792,   0,   0);

  // graph tail (fp32)
  hipMemsetAsync(adj1, 0, (65536 + 256)*sizeof(float), stream);
  build_adj_kernel<<<dim3(16),  256, 0, stream>>>(ei, adj1, cnt);
  sage12_kernel   <<<dim3(256), 128, 0, stream>>>(adj1, cnt, org, wt, s1bl, wt+32768,
                                                  wt+65536, s2bl, wt+98304, x1, s, st, entpart);
  fuse1_kernel    <<<dim3(448), 256, 0, stream>>>(s, x1, adj1, st, xp, t, linkpart);
  adjp_kernel     <<<dim3(128), 128, 0, stream>>>(s, t, adjp);
  binarize_kernel <<<dim3(128), 128, 0, stream>>>(adjp, d_out + 260, d_out + 16644, cols);
  sage3_agg_kernel<<<dim3(128), 128, 0, stream>>>(xp, cols, aggn3);
  sage3_out_kernel<<<dim3(128), 128, 0, stream>>>(aggn3, xp, s3wl, s3bl, s3wr, d_out + 4);
  finalize_kernel <<<dim3(1),   256, 0, stream>>>(linkpart, entpart, d_out);
}

// Round 13
// 209.857 us; speedup vs baseline: 2.4456x; 1.0513x over previous
//
#include <hip/hip_runtime.h>
#include <hip/hip_bf16.h>
#include <math.h>

#define N_EDGES 4096
#define NN1 256
#define NN2 128

typedef short v8s __attribute__((ext_vector_type(8)));
typedef float v4f __attribute__((ext_vector_type(4)));

__device__ inline unsigned short f2b(float f){
  union { __hip_bfloat16 h; unsigned short u; } cv;
  cv.h = __float2bfloat16(f);
  return cv.u;
}

// ---------------- reduction helpers ----------------
template<int NT>
__device__ inline float block_sum(float v, float* red, int t){
  red[t] = v; __syncthreads();
  #pragma unroll
  for (int st = NT/2; st > 0; st >>= 1){
    if (t < st) red[t] += red[t+st];
    __syncthreads();
  }
  float r = red[0]; __syncthreads();
  return r;
}
template<int NT>
__device__ inline float block_max(float v, float* red, int t){
  red[t] = v; __syncthreads();
  #pragma unroll
  for (int st = NT/2; st > 0; st >>= 1){
    if (t < st) red[t] = fmaxf(red[t], red[t+st]);
    __syncthreads();
  }
  float r = red[0]; __syncthreads();
  return r;
}
template<int NT>
__device__ inline int block_min_int(int v, int* red, int t){
  red[t] = v; __syncthreads();
  #pragma unroll
  for (int st = NT/2; st > 0; st >>= 1){
    if (t < st) red[t] = min(red[t], red[t+st]);
    __syncthreads();
  }
  int r = red[0]; __syncthreads();
  return r;
}

// ---------------- conv3x3(SAME) via bf16 MFMA implicit GEMM ----------------
// (unchanged from r12 - see r11 theory for layout derivation)
template<int CHUNKS, int COUT, int CIN, int SSLABS, int BSTR, int OUTF32>
__global__ __launch_bounds__(256) void conv_mfma(
    const unsigned short* __restrict__ in, const unsigned short* __restrict__ wb,
    const float* __restrict__ bias, unsigned short* __restrict__ outb,
    float* __restrict__ outf,
    int in_row, int in_slab, int out_row, int out_slab)
{
  constexpr int CG = COUT/32;
  __shared__ unsigned short tileb[SSLABS*2600];   // SSLABS slabs x 18x18 px x 8ci (+8 pad)
  __shared__ unsigned short wldsb[9*32*40];       // [k][co32][ci32 pad40]

  const int cg = blockIdx.x % CG, bx = blockIdx.x / CG, by = blockIdx.y;
  const int tid = threadIdx.x, lane = tid & 63, wv = tid >> 6;
  const int cot = wv >> 1, wp = wv & 1;
  const int ml = lane & 15, g = lane >> 4;

  v4f acc[8];
  #pragma unroll
  for (int t = 0; t < 8; ++t) acc[t] = (v4f){0.f,0.f,0.f,0.f};

  for (int cb = 0; cb < CHUNKS; ++cb){
    if (cb) __syncthreads();
    for (int j = tid; j < SSLABS*324; j += 256){
      int s = j / 324, rem = j - s*324;
      int row = rem / 18, px = rem - row*18;
      int gidx = (cb*SSLABS + s)*in_slab + ((by*16 + row)*in_row + bx*16 + px)*8;
      *(v8s*)&tileb[s*2600 + (row*18+px)*8] = *(const v8s*)&in[gidx];
    }
    for (int j = tid; j < 1152; j += 256){
      int k = j >> 7, rem = j & 127;
      int co = rem >> 2, q = rem & 3;
      int gw = (k*COUT + cg*32 + co)*CIN + cb*32 + q*8;
      *(v8s*)&wldsb[(k*32+co)*40 + q*8] = *(const v8s*)&wb[gw];
    }
    __syncthreads();

    #pragma unroll
    for (int k9 = 0; k9 < 9; ++k9){
      const int ky = k9/3, kx = k9 - 3*(k9/3);
      v8s a = *(const v8s*)&wldsb[(k9*32 + cot*16 + ml)*40 + g*8];
      #pragma unroll
      for (int tt = 0; tt < 8; ++tt){
        int t = wp*8 + tt;
        v8s b = *(const v8s*)&tileb[g*BSTR + ((t+ky)*18 + kx + ml)*8];
        acc[tt] = __builtin_amdgcn_mfma_f32_16x16x32_bf16(a, b, acc[tt], 0, 0, 0);
      }
    }
  }

  const int cob = cg*32 + cot*16 + g*4;
  float b4[4] = {bias[cob], bias[cob+1], bias[cob+2], bias[cob+3]};
  #pragma unroll
  for (int tp = 0; tp < 4; ++tp){
    float m[4];
    #pragma unroll
    for (int r = 0; r < 4; ++r){
      float v = fmaxf(acc[2*tp][r], acc[2*tp+1][r]);
      float o = __shfl_xor(v, 1);
      m[r] = fmaxf(fmaxf(v, o) + b4[r], 0.f);
    }
    if ((lane & 1) == 0){
      int gy = by*8 + wp*4 + tp, gx = bx*8 + (ml >> 1);
      if (OUTF32){
        #pragma unroll
        for (int r = 0; r < 4; ++r)
          outf[(cob + r)*256 + gy*16 + gx] = m[r];
      } else {
        unsigned int u0 = (unsigned)f2b(m[0]) | ((unsigned)f2b(m[1]) << 16);
        unsigned int u1 = (unsigned)f2b(m[2]) | ((unsigned)f2b(m[3]) << 16);
        int slabo = cob >> 3, sub = (g & 1)*4;
        size_t idx = (size_t)slabo*out_slab + (size_t)((gy+1)*out_row + gx+1)*8 + sub;
        *(uint2*)(outb + idx) = make_uint2(u0, u1);
      }
    }
  }
}

// ---------------- zero borders of the 5 bf16 slab buffers + adj/cnt region ----------
// Interiors are fully rewritten every launch; only halo rings need zeroing.
__global__ __launch_bounds__(256) void zero_kernel(unsigned short* __restrict__ wsb,
                                                   float* __restrict__ adjz)
{
  int j = blockIdx.x*256 + threadIdx.x;
  const int c0=2056, c1=6184, c2=10344, c3=14568, c4=18920, ca=35368;
  if (j >= ca) return;
  if (j >= c4){                       // adj1 + cnt: 65792 floats as float4
    int q = j - c4;
    ((float4*)adjz)[q] = make_float4(0.f,0.f,0.f,0.f);
    return;
  }
  int base, P, R, W, per, rem;
  if (j < c0)      { base=0;       P=516; R=514; W=512; per=2056; rem=j; }
  else if (j < c1) { base=2121792; P=260; R=258; W=256; per=1032; rem=j-c0; }
  else if (j < c2) { base=4268352; P=132; R=130; W=128; per=520;  rem=j-c1; }
  else if (j < c3) { base=5366592; P=68;  R=66;  W=64;  per=264;  rem=j-c2; }
  else             { base=5941056; P=36;  R=34;  W=32;  per=136;  rem=j-c3; }
  int s = rem / per, r2 = rem - s*per;
  int row, px;
  if (r2 < 2*P){ row = (r2 < P) ? 0 : R-1; px = (r2 < P) ? r2 : r2 - P; }
  else { int q = r2 - 2*P; row = 1 + (q >> 1); px = (q & 1) ? (W+1) : 0; }
  *(uint4*)&wsb[(size_t)base + ((size_t)(s*R + row)*P + px)*8] = make_uint4(0,0,0,0);
}

// ---------------- prep: pack input bf16, conv weights bf16 [k][co][ci], sage wT ----
__global__ __launch_bounds__(256) void prep_kernel(
    const float* __restrict__ src, unsigned short* __restrict__ p0b,
    const float* __restrict__ w1, const float* __restrict__ w2,
    const float* __restrict__ w3, const float* __restrict__ w4,
    const float* __restrict__ w5, unsigned short* __restrict__ wbb,
    const float* __restrict__ a, const float* __restrict__ b2,
    const float* __restrict__ c2, const float* __restrict__ d2,
    float* __restrict__ o)
{
  int b = blockIdx.x, tid = threadIdx.x;
  if (b < 1024){
    int idx = b*256 + tid;            // 0..262143: one pixel/thread
    int y = idx >> 9, x = idx & 511;
    unsigned short v8[8];
    #pragma unroll
    for (int c = 0; c < 5; ++c) v8[c] = f2b(src[c*262144 + y*512 + x]);
    v8[5] = 0; v8[6] = 0; v8[7] = 0;
    *(uint4*)&p0b[((size_t)(y+1)*516 + (x+1))*8] = *(uint4*)v8;
  } else if (b < 1452){
    int j = (b-1024)*256 + tid;   // 0..109567
    int co, ci, CO, CIl, CIsrc, dst; const float* w;
    if (j < 1024)      { co=j>>5;        ci=j&31;        w=w1; CIsrc=5;   CO=32;  CIl=32;  dst=0; }
    else if (j < 3072) { int q=j-1024;   co=q>>5;  ci=q&31;  w=w2; CIsrc=32;  CO=64;  CIl=32;  dst=9216; }
    else if (j < 11264){ int q=j-3072;   co=q>>6;  ci=q&63;  w=w3; CIsrc=64;  CO=128; CIl=64;  dst=27648; }
    else if (j < 44032){ int q=j-11264;  co=q>>7;  ci=q&127; w=w4; CIsrc=128; CO=256; CIl=128; dst=101376; }
    else               { int q=j-44032;  co=q>>8;  ci=q&255; w=w5; CIsrc=256; CO=256; CIl=256; dst=396288; }
    #pragma unroll
    for (int k = 0; k < 9; ++k){
      float val = (ci < CIsrc) ? w[(co*CIsrc + ci)*9 + k] : 0.f;
      wbb[dst + (k*CO + co)*CIl + ci] = f2b(val);
    }
  } else {
    int idx = (b-1452)*256 + tid;
    int m = idx >> 15, rem = idx & 32767, k = rem >> 7, cc = rem & 127;
    const float* sp = (m==0)?a:(m==1)?b2:(m==2)?c2:d2;
    o[m*32768 + k*128 + cc] = sp[cc*256 + k];
  }
}

// ---------------- graph kernels (fp32) ----------------
__global__ void build_adj_kernel(const int* __restrict__ ei, float* adj, float* cnt){
  int e = blockIdx.x*256 + threadIdx.x;
  if (e < N_EDGES){
    int s = ei[e], d = ei[N_EDGES + e];
    atomicAdd(&adj[s*NN1 + d], 1.0f);   // integer-valued -> order independent
    atomicAdd(&cnt[d], 1.0f);
  }
}

// sage12 with fused neighbor aggregation (branch-free exact-zero adds)
__global__ __launch_bounds__(128) void sage12_kernel(
    const float* __restrict__ adj, const float* __restrict__ cnt,
    const float* __restrict__ org,
    const float* __restrict__ wl1t, const float* __restrict__ bl1, const float* __restrict__ wr1t,
    const float* __restrict__ wl2t, const float* __restrict__ bl2, const float* __restrict__ wr2t,
    float* __restrict__ x1, float* __restrict__ s_out, float* __restrict__ st,
    float* __restrict__ entpart)
{
  __shared__ float sa[NN1], so[NN1], col[NN1], red[128];
  int n = blockIdx.x, c = threadIdx.x;
  for (int k = c; k < NN1; k += 128){
    col[k] = adj[k*NN1 + n];
    so[k]  = org[n*NN1 + k];
  }
  __syncthreads();
  float a0 = 0.f, a1 = 0.f;
  #pragma unroll 4
  for (int s2 = 0; s2 < NN1; ++s2){
    float av = col[s2];
    a0 += av * org[s2*NN1 + c];
    a1 += av * org[s2*NN1 + c + 128];
  }
  float cd = fmaxf(cnt[n], 1.0f);
  sa[c] = a0 / cd;
  sa[c+128] = a1 / cd;
  __syncthreads();

  float p1 = bl1[c], p2 = bl2[c];
  for (int k = 0; k < NN1; ++k){
    float av = sa[k], ov = so[k];
    p1 += av*wl1t[k*128+c] + ov*wr1t[k*128+c];
    p2 += av*wl2t[k*128+c] + ov*wr2t[k*128+c];
  }
  float n1s = block_sum<128>(p1*p1, red, c);
  x1[n*128 + c] = p1 / fmaxf(sqrtf(n1s), 1e-12f);
  float n2s = block_sum<128>(p2*p2, red, c);
  float p2n = p2 / fmaxf(sqrtf(n2s), 1e-12f);
  float mx = block_max<128>(p2n, red, c);
  float ev = expf(p2n - mx);
  float ssum = block_sum<128>(ev, red, c);
  float sv = ev / ssum;
  s_out[n*128 + c] = sv;
  st[c*NN1 + n] = sv;
  float esum = block_sum<128>(-sv * logf(sv + 1e-15f), red, c);
  if (c == 0) entpart[n] = esum;
}

// fused: xp (64 blk) | adj_s (128 blk) | link (256 blk)
__global__ __launch_bounds__(256) void fuse1_kernel(
    const float* __restrict__ s, const float* __restrict__ x1,
    const float* __restrict__ adj, const float* __restrict__ st,
    float* __restrict__ xp, float* __restrict__ t, float* __restrict__ linkpart)
{
  __shared__ float sn[128]; __shared__ float red[256];
  int b = blockIdx.x, tid = threadIdx.x;
  if (b < 64){
    int cc = b*2 + (tid >> 7), f = tid & 127;
    float acc = 0.f;
    for (int n = 0; n < NN1; ++n) acc += s[n*128+cc] * x1[n*128+f];
    xp[cc*128+f] = acc;
  } else if (b < 192){
    int n = (b-64)*2 + (tid >> 7), c = tid & 127;
    float acc = 0.f;
    for (int m = 0; m < NN1; ++m){
      float a = adj[n*NN1+m];
      if (a != 0.f) acc += a * s[m*128+c];
    }
    t[n*128+c] = acc;
  } else {
    int n = b - 192, m = tid;
    if (m < 128) sn[m] = s[n*128+m];
    __syncthreads();
    float dot = 0.f;
    for (int c = 0; c < 128; ++c) dot += sn[c]*st[c*NN1 + m];
    float v = adj[n*NN1+m] - dot;
    float part = block_sum<256>(v*v, red, m);
    if (m == 0) linkpart[n] = part;
  }
}

// fused adjp + binarize: block cc computes adjp row cc then binarizes it.
// Same n-ascending sum order as the old adjp_kernel -> bit-identical values.
__global__ __launch_bounds__(128) void adjp_bin_kernel(
    const float* __restrict__ s, const float* __restrict__ t,
    float* __restrict__ edge_out, float* __restrict__ ei2_out, int* __restrict__ cols)
{
  __shared__ float scol[NN1]; __shared__ float red[128]; __shared__ int redi[128];
  int cc = blockIdx.x, j = threadIdx.x;
  scol[j]       = s[j*128 + cc];
  scol[j + 128] = s[(j+128)*128 + cc];
  __syncthreads();
  float acc = 0.f;
  for (int n = 0; n < NN1; ++n) acc += scol[n] * t[n*128 + j];
  float mx = block_max<128>(acc, red, j);
  edge_out[cc*128+j] = (acc == mx) ? 1.0f : 0.0f;
  int cand = (acc == mx) ? j : (1 << 30);
  int cmin = block_min_int<128>(cand, redi, j);
  if (j == 0){
    cols[cc] = cmin;
    ei2_out[cc] = (float)cc;
    ei2_out[128 + cc] = (float)cmin;
  }
}

// fused sage3 agg + out: block n recomputes aggn3 row n (identical i-order), then
// the two dot products + L2norm + tanh.
__global__ __launch_bounds__(128) void sage3_kernel(
    const float* __restrict__ xp, const int* __restrict__ cols,
    const float* __restrict__ wl3, const float* __restrict__ bl3,
    const float* __restrict__ wr3, float* __restrict__ nodes_out)
{
  __shared__ int colsl[NN2]; __shared__ float red[128];
  int n = blockIdx.x, f = threadIdx.x;
  colsl[f] = cols[f];
  __syncthreads();
  float acc = 0.f, c = 0.f;
  for (int i = 0; i < NN2; ++i){
    if (colsl[i] == n){ acc += xp[i*128+f]; c += 1.f; }
  }
  float ag = acc / fmaxf(c, 1.f);
  float xv = xp[n*128+f];
  float q0 = block_sum<128>(ag*wl3[f]     + xv*wr3[f],     red, f);
  float q1 = block_sum<128>(ag*wl3[128+f] + xv*wr3[128+f], red, f);
  if (f == 0){
    float p0 = q0 + bl3[0], p1 = q1 + bl3[1];
    float nm = fmaxf(sqrtf(p0*p0 + p1*p1), 1e-12f);
    nodes_out[n*2+0] = tanhf(p0/nm);
    nodes_out[n*2+1] = tanhf(p1/nm);
  }
}

__global__ __launch_bounds__(256) void finalize_kernel(const float* __restrict__ linkpart,
    const float* __restrict__ entpart, float* __restrict__ d_out)
{
  __shared__ float red[256];
  int t = threadIdx.x;
  float ls = block_sum<256>(linkpart[t], red, t);
  float es = block_sum<256>(entpart[t], red, t);
  float v0 = 0.f, v1 = 0.f;
  if (t < 128){ v0 = d_out[4 + t*2 + 0]; v1 = d_out[4 + t*2 + 1]; }
  float s0 = block_sum<256>(v0, red, t);
  float s1 = block_sum<256>(v1, red, t);
  if (t == 0){
    d_out[0] = s0;
    d_out[1] = s1;
    d_out[2] = sqrtf(ls)/65536.0f + sqrtf(16256.0f)/16384.0f;  // ll1 + ll2(const)
    d_out[3] = es/256.0f;                                      // el1 + el2(=0)
  }
}

extern "C" void kernel_launch(void* const* d_in, const int* in_sizes, int n_in,
                              void* d_out_v, int out_size, void* d_ws, size_t ws_size,
                              hipStream_t stream)
{
  (void)in_sizes; (void)n_in; (void)out_size; (void)ws_size;
  const float* input = (const float*)d_in[0];
  const int*   ei    = (const int*)  d_in[1];
  const float* w1 = (const float*)d_in[2];  const float* b1 = (const float*)d_in[3];
  const float* w2 = (const float*)d_in[4];  const float* b2 = (const float*)d_in[5];
  const float* w3 = (const float*)d_in[6];  const float* b3 = (const float*)d_in[7];
  const float* w4 = (const float*)d_in[8];  const float* b4 = (const float*)d_in[9];
  const float* w5 = (const float*)d_in[10]; const float* b5 = (const float*)d_in[11];
  const float* s1wl = (const float*)d_in[12]; const float* s1bl = (const float*)d_in[13];
  const float* s1wr = (const float*)d_in[14];
  const float* s2wl = (const float*)d_in[15]; const float* s2bl = (const float*)d_in[16];
  const float* s2wr = (const float*)d_in[17];
  const float* s3wl = (const float*)d_in[18]; const float* s3bl = (const float*)d_in[19];
  const float* s3wr = (const float*)d_in[20];
  float* d_out = (float*)d_out_v;
  float* ws = (float*)d_ws;

  // f32-unit offsets (bf16 buffers use 2 bf16 per unit)
  unsigned short* P0b = (unsigned short*)(ws);
  unsigned short* Pb1 = (unsigned short*)(ws + 1060896);
  unsigned short* Pb2 = (unsigned short*)(ws + 2134176);
  unsigned short* Pb3 = (unsigned short*)(ws + 2683296);
  unsigned short* Pb4 = (unsigned short*)(ws + 2970528);
  unsigned short* wb  = (unsigned short*)(ws + 3127200);
  float* org = ws + 3620256;
  float* wt  = ws + 3685792;
  float* st  = ws + 3816864;
  float* G   = ws + 3849632;

  float* adj1     = G;                   // 65,536
  float* cnt      = G + 65536;           // 256
  float* x1       = G + 147712;          // 32,768
  float* s        = G + 180480;          // 32,768
  float* t        = G + 213248;          // 32,768
  float* xp       = G + 246016;          // 16,384
  int*   cols     = (int*)(G + 278784);  // 128
  float* linkpart = G + 278912;          // 256
  float* entpart  = G + 279168;          // 256

  // zero only what each launch needs zeroed: buffer halo rings + adj/cnt
  zero_kernel<<<dim3(139), 256, 0, stream>>>((unsigned short*)ws, adj1);
  // prep: pack input bf16 (1024) + conv weights (428) + sage wT (512)
  prep_kernel<<<dim3(1964), 256, 0, stream>>>(input, P0b, w1, w2, w3, w4, w5, wb,
                                              s1wl, s1wr, s2wl, s2wr, wt);

  // conv stack (bf16 MFMA):   grid = (W/16 * COUT/32, H/16)
  conv_mfma<1,32,32,1,0,0>      <<<dim3(32,32), 256, 0, stream>>>(P0b, wb,        b1, Pb1, nullptr, 516, 2121792, 260, 536640);
  conv_mfma<1,64,32,4,2600,0>   <<<dim3(32,16), 256, 0, stream>>>(Pb1, wb+9216,   b2, Pb2, nullptr, 260, 536640, 132, 137280);
  conv_mfma<2,128,64,4,2600,0>  <<<dim3(32,8),  256, 0, stream>>>(Pb2, wb+27648,  b3, Pb3, nullptr, 132, 137280, 68,  35904);
  conv_mfma<4,256,128,4,2600,0> <<<dim3(32,4),  256, 0, stream>>>(Pb3, wb+101376, b4, Pb4, nullptr, 68,  35904,  36,  9792);
  conv_mfma<8,256,256,4,2600,1> <<<dim3(16,2),  256, 0, stream>>>(Pb4, wb+396288, b5, nullptr, org, 36,  9792,   0,   0);

  // graph tail (fp32)
  build_adj_kernel<<<dim3(16),  256, 0, stream>>>(ei, adj1, cnt);
  sage12_kernel   <<<dim3(256), 128, 0, stream>>>(adj1, cnt, org, wt, s1bl, wt+32768,
                                                  wt+65536, s2bl, wt+98304, x1, s, st, entpart);
  fuse1_kernel    <<<dim3(448), 256, 0, stream>>>(s, x1, adj1, st, xp, t, linkpart);
  adjp_bin_kernel <<<dim3(128), 128, 0, stream>>>(s, t, d_out + 260, d_out + 16644, cols);
  sage3_kernel    <<<dim3(128), 128, 0, stream>>>(xp, cols, s3wl, s3bl, s3wr, d_out + 4);
  finalize_kernel <<<dim3(1),   256, 0, stream>>>(linkpart, entpart, d_out);
}